// Round 1
// baseline (370.698 us; speedup 1.0000x reference)
//
#include <hip/hip_runtime.h>
#include <hip/hip_bf16.h>
#include <cstdint>
#include <cstddef>

typedef __hip_bfloat16 bf16;
typedef __attribute__((ext_vector_type(8))) short short8;   // 8 bf16 = 4 VGPRs
typedef __attribute__((ext_vector_type(4))) float floatx4;

#define B_ 2
#define S_ 2048
#define D_ 1024
#define H_ 16
#define DK_ 64
#define M_ 4096

struct __align__(8) bf16x4 { bf16 x, y, z, w; };

__device__ __forceinline__ floatx4 mfma16(short8 a, short8 b, floatx4 c) {
  return __builtin_amdgcn_mfma_f32_16x16x32_bf16(a, b, c, 0, 0, 0);
}

// async global->LDS, 16B per lane; LDS dest is wave-uniform base + lane*16
__device__ __forceinline__ void gl_lds16(const bf16* g, bf16* l) {
  __builtin_amdgcn_global_load_lds((const __attribute__((address_space(1))) void*)g,
                                   (__attribute__((address_space(3))) void*)l,
                                   16, 0, 0);
}

// ---------------- elementwise fp32 -> bf16 ----------------
__global__ void convert_f32_bf16(const float* __restrict__ src, bf16* __restrict__ dst,
                                 const int n4) {
  const int i = blockIdx.x * blockDim.x + threadIdx.x;
  if (i >= n4) return;
  float4 v = ((const float4*)src)[i];
  bf16x4 o = { __float2bfloat16(v.x), __float2bfloat16(v.y),
               __float2bfloat16(v.z), __float2bfloat16(v.w) };
  ((bf16x4*)dst)[i] = o;
}

// ---------------- transpose fp32 [R][C] -> bf16 [C][R] (for weights) ----------------
__global__ void transpose_convert(const float* __restrict__ src, bf16* __restrict__ dst,
                                  const int R, const int C) {
  __shared__ bf16 tile[64][66];   // pad 66: conflict-free transposed reads
  const int r0 = blockIdx.y * 64, c0 = blockIdx.x * 64;
  const int tid = threadIdx.x;
  const int lr = tid >> 4;            // 0..15
  const int lc4 = (tid & 15) * 4;     // 0..60
#pragma unroll
  for (int i = 0; i < 4; ++i) {
    const int r = lr + i * 16;
    float4 v = *(const float4*)(src + (size_t)(r0 + r) * C + c0 + lc4);
    tile[r][lc4 + 0] = __float2bfloat16(v.x);
    tile[r][lc4 + 1] = __float2bfloat16(v.y);
    tile[r][lc4 + 2] = __float2bfloat16(v.z);
    tile[r][lc4 + 3] = __float2bfloat16(v.w);
  }
  __syncthreads();
  const int orr = tid & 63;
  const int oc0 = tid >> 6;
#pragma unroll
  for (int j = 0; j < 16; ++j) {
    const int oc = oc0 + j * 4;
    dst[(size_t)(c0 + oc) * R + r0 + orr] = tile[orr][oc];
  }
}

// ---------------- padding-mask dtype detector ----------------
// flag=1 iff buffer looks like packed bool bytes (a 0x01 in bytes 1..3 of some word,
// with all bytes in {0,1}). int32 bools (0/1) and float 1.0f never match.
// If mask is float32 and flag==0, int32 nonzero-test still gives the right answer.
__global__ void detect_mask(const unsigned int* __restrict__ p, int* __restrict__ flag) {
  __shared__ int sbyte;
  if (threadIdx.x == 0) sbyte = 0;
  __syncthreads();
  for (int i = threadIdx.x; i < (B_ * S_) / 4; i += 256) {
    const unsigned int v = p[i];
    if (((v & 0xFEFEFEFEu) == 0u) && ((v & 0xFFFFFF00u) != 0u)) sbyte = 1;
  }
  __syncthreads();
  if (threadIdx.x == 0) *flag = sbyte;
}

// ---------------- bf16 GEMM, C = A[M,K] * Bt[N,K]^T + bias ----------------
// MODE 0: bf16 out in [B][H][S][DK]   (Q/K projections)
// MODE 1: bf16 out in [B][H][DK][S]   (V projection, transposed for PV)
// MODE 2: fp32 out in [M][N]          (final output projection)
template <int MODE>
__global__ __launch_bounds__(256, 2) void gemm_bt(
    const bf16* __restrict__ A, const bf16* __restrict__ Bt,
    const float* __restrict__ bias, void* __restrict__ Cout,
    const int Mdim, const int Ndim, const int Kdim)
{
  __shared__ __align__(16) bf16 As[128 * 32];
  __shared__ __align__(16) bf16 Bs[128 * 32];
  const int tid = threadIdx.x;
  const int wave = tid >> 6, lane = tid & 63;
  const int quad = lane >> 4, lc = lane & 15;
  const int wm = (wave >> 1) * 64, wn = (wave & 1) * 64;
  const int m0 = blockIdx.y * 128, n0 = blockIdx.x * 128;

  const floatx4 zero4 = {0.f, 0.f, 0.f, 0.f};
  floatx4 acc[4][4];
#pragma unroll
  for (int mi = 0; mi < 4; ++mi)
#pragma unroll
    for (int ni = 0; ni < 4; ++ni) acc[mi][ni] = zero4;

  const int ldr = lane >> 2;          // 16 rows per wave-chunk
  const int ldc = (lane & 3) * 8;     // 4 x 8 bf16 = 64B row
  const bf16* Ag = A + (size_t)(m0 + wave * 32 + ldr) * Kdim + ldc;
  const bf16* Bg = Bt + (size_t)(n0 + wave * 32 + ldr) * Kdim + ldc;
  bf16* As0 = As + wave * 32 * 32;
  bf16* Bs0 = Bs + wave * 32 * 32;

  for (int k0 = 0; k0 < Kdim; k0 += 32) {
    gl_lds16(Ag + k0, As0);
    gl_lds16(Ag + k0 + (size_t)16 * Kdim, As0 + 16 * 32);
    gl_lds16(Bg + k0, Bs0);
    gl_lds16(Bg + k0 + (size_t)16 * Kdim, Bs0 + 16 * 32);
    __syncthreads();

    short8 af[4], bfr[4];
#pragma unroll
    for (int i = 0; i < 4; ++i) {
      af[i]  = *(const short8*)(As + (wm + i * 16 + lc) * 32 + quad * 8);
      bfr[i] = *(const short8*)(Bs + (wn + i * 16 + lc) * 32 + quad * 8);
    }
#pragma unroll
    for (int mi = 0; mi < 4; ++mi)
#pragma unroll
      for (int ni = 0; ni < 4; ++ni)
        acc[mi][ni] = mfma16(af[mi], bfr[ni], acc[mi][ni]);
    __syncthreads();
  }

  // epilogue: C row = m0+wm+mi*16+quad*4+r, col = n0+wn+ni*16+lc
#pragma unroll
  for (int mi = 0; mi < 4; ++mi)
#pragma unroll
    for (int ni = 0; ni < 4; ++ni) {
      const int col = n0 + wn + ni * 16 + lc;
      const float bv = bias[col];
      const int rbase = m0 + wm + mi * 16 + quad * 4;
      if (MODE == 2) {
        float* out = (float*)Cout;
#pragma unroll
        for (int r = 0; r < 4; ++r)
          out[(size_t)(rbase + r) * Ndim + col] = acc[mi][ni][r] + bv;
      } else if (MODE == 0) {
        bf16* out = (bf16*)Cout;
        const int hh = col >> 6, dk = col & 63;
#pragma unroll
        for (int r = 0; r < 4; ++r) {
          const int m = rbase + r, bb = m >> 11, ss = m & (S_ - 1);
          out[((((size_t)bb * H_ + hh) * S_ + ss) * DK_) + dk] =
              __float2bfloat16(acc[mi][ni][r] + bv);
        }
      } else {  // MODE 1: [B][H][DK][S], 4 consecutive s per lane -> one 8B store
        bf16* out = (bf16*)Cout;
        const int hh = col >> 6, dk = col & 63;
        const int bb = rbase >> 11, ss = rbase & (S_ - 1);
        bf16x4 pk = { __float2bfloat16(acc[mi][ni][0] + bv),
                      __float2bfloat16(acc[mi][ni][1] + bv),
                      __float2bfloat16(acc[mi][ni][2] + bv),
                      __float2bfloat16(acc[mi][ni][3] + bv) };
        *(bf16x4*)(out + (((size_t)bb * H_ + hh) * DK_ + dk) * S_ + ss) = pk;
      }
    }
}

// ---------------- fused attention ----------------
// qp/kp: [B][H][S][DK] bf16, vt: [B][H][DK][S] bf16, o: [B][S][H][DK] bf16
// softmax uses logit 1e-10 for masked (causal j>i, padding on keys); no max-sub
// needed since |logit| <= ~3 -> exp in [0.05, 20], no overflow. Single pass:
// O += exp(s)*V, l += row-sum(exp(s)); normalize at end.
__global__ __launch_bounds__(256, 2) void attn_kernel(
    const bf16* __restrict__ qp, const bf16* __restrict__ kp,
    const bf16* __restrict__ vt, const void* __restrict__ pad,
    const int* __restrict__ flag, bf16* __restrict__ o)
{
  __shared__ __align__(16) bf16 Ks[64 * 64];       // [s_local][dk]
  __shared__ __align__(16) bf16 Vs[64 * 64];       // [dk][s_local]
  __shared__ __align__(16) bf16 Ps[4][16 * 64];    // per-wave P tile [qrow][s_local]

  const int b = blockIdx.z, h = blockIdx.y;
  const int q0 = blockIdx.x * 64;
  const int tid = threadIdx.x;
  const int wave = tid >> 6, lane = tid & 63;
  const int quad = lane >> 4, lc = lane & 15;
  const int bytemode = *flag;
  const int padbase = b * S_;

  const size_t headoff = ((size_t)b * H_ + h) * (size_t)(S_ * DK_);

  // Q fragments (A-layout: m=lc, k=quad*8+j), loaded once from global
  const bf16* qrow = qp + headoff + (size_t)(q0 + wave * 16 + lc) * DK_;
  const short8 aq0 = *(const short8*)(qrow + quad * 8);
  const short8 aq1 = *(const short8*)(qrow + 32 + quad * 8);

  // staging addresses: 8 rows x 128B per wave-chunk
  const int srow = wave * 16 + (lane >> 3);
  const int scol = (lane & 7) * 8;
  const bf16* kg = kp + headoff + (size_t)srow * DK_ + scol;
  const bf16* vg = vt + headoff + (size_t)srow * S_ + scol;
  bf16* ksb = Ks + wave * 16 * 64;
  bf16* vsb = Vs + wave * 16 * 64;

  const floatx4 zero4 = {0.f, 0.f, 0.f, 0.f};
  floatx4 oacc[4];
#pragma unroll
  for (int i = 0; i < 4; ++i) oacc[i] = zero4;
  float lacc[4] = {0.f, 0.f, 0.f, 0.f};

  for (int k0 = 0; k0 < S_; k0 += 64) {
    gl_lds16(kg + (size_t)k0 * DK_, ksb);
    gl_lds16(kg + (size_t)(k0 + 8) * DK_, ksb + 8 * 64);
    gl_lds16(vg + k0, vsb);
    gl_lds16(vg + k0 + 8 * S_, vsb + 8 * 64);
    __syncthreads();

    // S = Q * K^T  (16 q-rows x 64 keys per wave)
    floatx4 sacc[4];
#pragma unroll
    for (int nt = 0; nt < 4; ++nt) {
      sacc[nt] = zero4;
      const short8 b0 = *(const short8*)(Ks + (nt * 16 + lc) * 64 + quad * 8);
      const short8 b1 = *(const short8*)(Ks + (nt * 16 + lc) * 64 + 32 + quad * 8);
      sacc[nt] = mfma16(aq0, b0, sacc[nt]);
      sacc[nt] = mfma16(aq1, b1, sacc[nt]);
    }

    // mask + exp; write P (bf16) to LDS in [qrow][s_local]; partial row sums
    float rs[4] = {0.f, 0.f, 0.f, 0.f};
#pragma unroll
    for (int nt = 0; nt < 4; ++nt) {
      const int kgidx = k0 + nt * 16 + lc;
      bool pm;
      if (bytemode) pm = ((const unsigned char*)pad)[padbase + kgidx] != 0;
      else          pm = ((const int*)pad)[padbase + kgidx] != 0;
#pragma unroll
      for (int r = 0; r < 4; ++r) {
        const int qg = q0 + wave * 16 + quad * 4 + r;
        float sv = sacc[nt][r] * 0.125f;
        if (pm || (kgidx > qg)) sv = 1e-10f;
        const float p = __expf(sv);
        rs[r] += p;
        Ps[wave][(quad * 4 + r) * 64 + nt * 16 + lc] = __float2bfloat16(p);
      }
    }
    // row sum: butterfly across the 16 lanes of this quad-group
#pragma unroll
    for (int r = 0; r < 4; ++r) {
      float v = rs[r];
      v += __shfl_xor(v, 1, 16);
      v += __shfl_xor(v, 2, 16);
      v += __shfl_xor(v, 4, 16);
      v += __shfl_xor(v, 8, 16);
      lacc[r] += v;
    }

    // O += P * V
    const short8 pa0 = *(const short8*)(&Ps[wave][lc * 64 + quad * 8]);
    const short8 pa1 = *(const short8*)(&Ps[wave][lc * 64 + 32 + quad * 8]);
#pragma unroll
    for (int nt = 0; nt < 4; ++nt) {
      const short8 b0 = *(const short8*)(Vs + (nt * 16 + lc) * 64 + quad * 8);
      const short8 b1 = *(const short8*)(Vs + (nt * 16 + lc) * 64 + 32 + quad * 8);
      oacc[nt] = mfma16(pa0, b0, oacc[nt]);
      oacc[nt] = mfma16(pa1, b1, oacc[nt]);
    }
    __syncthreads();
  }

  // normalize and write [B][S][H][DK]
#pragma unroll
  for (int nt = 0; nt < 4; ++nt)
#pragma unroll
    for (int r = 0; r < 4; ++r) {
      const int qg = q0 + wave * 16 + quad * 4 + r;
      const float val = oacc[nt][r] / lacc[r];
      o[(((size_t)b * S_ + qg) * H_ + h) * DK_ + nt * 16 + lc] = __float2bfloat16(val);
    }
}

extern "C" void kernel_launch(void* const* d_in, const int* in_sizes, int n_in,
                              void* d_out, int out_size, void* d_ws, size_t ws_size,
                              hipStream_t stream) {
  (void)in_sizes; (void)n_in; (void)out_size; (void)ws_size;
  const float* q_in = (const float*)d_in[0];
  const float* k_in = (const float*)d_in[1];
  const float* v_in = (const float*)d_in[2];
  const void*  pmask = d_in[3];
  const float* Wq = (const float*)d_in[4];
  const float* bq = (const float*)d_in[5];
  const float* Wk = (const float*)d_in[6];
  const float* bk = (const float*)d_in[7];
  const float* Wv = (const float*)d_in[8];
  const float* bv = (const float*)d_in[9];
  const float* Wo = (const float*)d_in[10];
  const float* bo = (const float*)d_in[11];

  char* ws = (char*)d_ws;
  bf16* xq  = (bf16*)(ws + 0);          // 8 MiB; reused later as attention output
  bf16* xk  = (bf16*)(ws + 8388608);    // 8 MiB
  bf16* xv  = (bf16*)(ws + 16777216);   // 8 MiB
  bf16* wqt = (bf16*)(ws + 25165824);   // 2 MiB each
  bf16* wkt = (bf16*)(ws + 27262976);
  bf16* wvt = (bf16*)(ws + 29360128);
  bf16* wot = (bf16*)(ws + 31457280);
  bf16* qpp = (bf16*)(ws + 33554432);   // 8 MiB
  bf16* kpp = (bf16*)(ws + 41943040);   // 8 MiB
  bf16* vtp = (bf16*)(ws + 50331648);   // 8 MiB
  int*  flg = (int*)(ws + 58720256);    // 4 B
  bf16* oa  = xq;                       // xq dead after Q projection

  const int n4 = (M_ * D_) / 4;         // 1048576
  convert_f32_bf16<<<4096, 256, 0, stream>>>(q_in, xq, n4);
  convert_f32_bf16<<<4096, 256, 0, stream>>>(k_in, xk, n4);
  convert_f32_bf16<<<4096, 256, 0, stream>>>(v_in, xv, n4);
  transpose_convert<<<dim3(16, 16), 256, 0, stream>>>(Wq, wqt, D_, D_);
  transpose_convert<<<dim3(16, 16), 256, 0, stream>>>(Wk, wkt, D_, D_);
  transpose_convert<<<dim3(16, 16), 256, 0, stream>>>(Wv, wvt, D_, D_);
  transpose_convert<<<dim3(16, 16), 256, 0, stream>>>(Wo, wot, D_, D_);
  detect_mask<<<1, 256, 0, stream>>>((const unsigned int*)pmask, flg);

  gemm_bt<0><<<dim3(8, 32), 256, 0, stream>>>(xq, wqt, bq, qpp, M_, D_, D_);
  gemm_bt<0><<<dim3(8, 32), 256, 0, stream>>>(xk, wkt, bk, kpp, M_, D_, D_);
  gemm_bt<1><<<dim3(8, 32), 256, 0, stream>>>(xv, wvt, bv, vtp, M_, D_, D_);

  attn_kernel<<<dim3(32, 16, 2), 256, 0, stream>>>(qpp, kpp, vtp, pmask, flg, oa);

  gemm_bt<2><<<dim3(8, 32), 256, 0, stream>>>(oa, wot, bo, (float*)d_out, M_, D_, D_);
}

// Round 2
// 276.066 us; speedup vs baseline: 1.3428x; 1.3428x over previous
//
#include <hip/hip_runtime.h>
#include <hip/hip_bf16.h>
#include <cstdint>
#include <cstddef>

typedef __hip_bfloat16 bf16;
typedef __attribute__((ext_vector_type(8))) short short8;   // 8 bf16 = 4 VGPRs
typedef __attribute__((ext_vector_type(4))) short s4v;      // 4 bf16 = 2 VGPRs
typedef __attribute__((ext_vector_type(4))) float floatx4;

#define B_ 2
#define S_ 2048
#define D_ 1024
#define H_ 16
#define DK_ 64
#define M_ 4096
#define HEADELEMS 131072   // S_*DK_ per (b,h)
#define TILEELEMS 4096     // 64*64 per 64-token tile

struct __align__(8) bf16x4 { bf16 x, y, z, w; };

__device__ __forceinline__ floatx4 mfma16(short8 a, short8 b, floatx4 c) {
  return __builtin_amdgcn_mfma_f32_16x16x32_bf16(a, b, c, 0, 0, 0);
}
__device__ __forceinline__ void gl_lds16(const bf16* g, bf16* l) {
  __builtin_amdgcn_global_load_lds((const __attribute__((address_space(1))) void*)g,
                                   (__attribute__((address_space(3))) void*)l, 16, 0, 0);
}
__device__ __forceinline__ short f2bs(float x) {
  bf16 b = __float2bfloat16(x);
  return *reinterpret_cast<short*>(&b);
}
__device__ __forceinline__ float bs2f(short s) {
  bf16 b = *reinterpret_cast<bf16*>(&s);
  return __bfloat162float(b);
}

// ---------------- fused fp32->bf16 converts (q,k,v inputs) ----------------
__global__ void convert3(const float* __restrict__ a0, const float* __restrict__ a1,
                         const float* __restrict__ a2, bf16* __restrict__ o0,
                         bf16* __restrict__ o1, bf16* __restrict__ o2, const int n4) {
  const int z = blockIdx.z;
  const float* src = (z == 0) ? a0 : (z == 1) ? a1 : a2;
  bf16* dst = (z == 0) ? o0 : (z == 1) ? o1 : o2;
  const int i = blockIdx.x * blockDim.x + threadIdx.x;
  if (i >= n4) return;
  float4 v = ((const float4*)src)[i];
  bf16x4 o = { __float2bfloat16(v.x), __float2bfloat16(v.y),
               __float2bfloat16(v.z), __float2bfloat16(v.w) };
  ((bf16x4*)dst)[i] = o;
}

// ---------------- fused weight transposes fp32 [R][C] -> bf16 [C][R] ----------------
__global__ void transpose4(const float* __restrict__ s0, const float* __restrict__ s1,
                           const float* __restrict__ s2, const float* __restrict__ s3,
                           bf16* __restrict__ d0, bf16* __restrict__ d1,
                           bf16* __restrict__ d2, bf16* __restrict__ d3) {
  const int z = blockIdx.z;
  const float* src = (z == 0) ? s0 : (z == 1) ? s1 : (z == 2) ? s2 : s3;
  bf16* dst = (z == 0) ? d0 : (z == 1) ? d1 : (z == 2) ? d2 : d3;
  __shared__ bf16 tile[64][66];
  const int r0 = blockIdx.y * 64, c0 = blockIdx.x * 64;
  const int tid = threadIdx.x;
  const int lr = tid >> 4;
  const int lc4 = (tid & 15) * 4;
#pragma unroll
  for (int i = 0; i < 4; ++i) {
    const int r = lr + i * 16;
    float4 v = *(const float4*)(src + (size_t)(r0 + r) * D_ + c0 + lc4);
    tile[r][lc4 + 0] = __float2bfloat16(v.x);
    tile[r][lc4 + 1] = __float2bfloat16(v.y);
    tile[r][lc4 + 2] = __float2bfloat16(v.z);
    tile[r][lc4 + 3] = __float2bfloat16(v.w);
  }
  __syncthreads();
  const int orr = tid & 63;
  const int oc0 = tid >> 6;
#pragma unroll
  for (int j = 0; j < 16; ++j) {
    const int oc = oc0 + j * 4;
    dst[(size_t)(c0 + oc) * D_ + r0 + orr] = tile[orr][oc];
  }
}

// ---------------- padding-mask dtype detector ----------------
__global__ void detect_mask(const unsigned int* __restrict__ p, int* __restrict__ flag) {
  __shared__ int sbyte;
  if (threadIdx.x == 0) sbyte = 0;
  __syncthreads();
  for (int i = threadIdx.x; i < (B_ * S_) / 4; i += 256) {
    const unsigned int v = p[i];
    if (((v & 0xFEFEFEFEu) == 0u) && ((v & 0xFFFFFF00u) != 0u)) sbyte = 1;
  }
  __syncthreads();
  if (threadIdx.x == 0) *flag = sbyte;
}

// ---------------- bf16 GEMM, C = A[M,K] * W[N,K]^T + bias ----------------
// mode 0: bf16 out, Q/K fragment-swizzled per-head tiles
// mode 1: bf16 out, V^T fragment-swizzled per-head tiles
// mode 2: fp32 out, plain [M][N]
// z = blockIdx.z selects A/W/bias/out; z==2 forces mode 1 (V), else mode01.
template<int MT>
__global__ __launch_bounds__(256, 2) void gemm_k(
    const bf16* __restrict__ A0, const bf16* __restrict__ A1, const bf16* __restrict__ A2,
    const bf16* __restrict__ W0, const bf16* __restrict__ W1, const bf16* __restrict__ W2,
    const float* __restrict__ b0, const float* __restrict__ b1, const float* __restrict__ b2,
    void* __restrict__ O0, void* __restrict__ O1, void* __restrict__ O2,
    const int mode01, const int Kd)
{
  __shared__ __align__(16) bf16 As[MT * 32];
  __shared__ __align__(16) bf16 Bs[128 * 32];
  const int z = blockIdx.z;
  const bf16* A = (z == 0) ? A0 : (z == 1) ? A1 : A2;
  const bf16* W = (z == 0) ? W0 : (z == 1) ? W1 : W2;
  const float* bias = (z == 0) ? b0 : (z == 1) ? b1 : b2;
  void* Cout = (z == 0) ? O0 : (z == 1) ? O1 : O2;
  const int mode = (z == 2) ? 1 : mode01;

  constexpr int MI = MT / 32;   // m-tiles per wave
  const int tid = threadIdx.x;
  const int wave = tid >> 6, lane = tid & 63;
  const int quad = lane >> 4, lc = lane & 15;
  const int wm = (wave >> 1) * (MT / 2), wn = (wave & 1) * 64;
  const int m0 = blockIdx.y * MT, n0 = blockIdx.x * 128;

  const floatx4 zero4 = {0.f, 0.f, 0.f, 0.f};
  floatx4 acc[MI][4];
#pragma unroll
  for (int mi = 0; mi < MI; ++mi)
#pragma unroll
    for (int ni = 0; ni < 4; ++ni) acc[mi][ni] = zero4;

  const int ldr = lane >> 2;
  const int ldc = (lane & 3) * 8;
  const bf16* Ag = A + (size_t)(m0 + wave * (MT / 4) + ldr) * Kd + ldc;
  const bf16* Bg = W + (size_t)(n0 + wave * 32 + ldr) * Kd + ldc;
  bf16* As0 = As + wave * (MT / 4) * 32;
  bf16* Bs0 = Bs + wave * 32 * 32;

  for (int k0 = 0; k0 < Kd; k0 += 32) {
    gl_lds16(Ag + k0, As0);
    if (MT == 128) gl_lds16(Ag + k0 + (size_t)16 * Kd, As0 + 16 * 32);
    gl_lds16(Bg + k0, Bs0);
    gl_lds16(Bg + k0 + (size_t)16 * Kd, Bs0 + 16 * 32);
    __syncthreads();

    short8 af[MI], bfr[4];
#pragma unroll
    for (int i = 0; i < MI; ++i)
      af[i] = *(const short8*)(As + (wm + i * 16 + lc) * 32 + quad * 8);
#pragma unroll
    for (int i = 0; i < 4; ++i)
      bfr[i] = *(const short8*)(Bs + (wn + i * 16 + lc) * 32 + quad * 8);
#pragma unroll
    for (int mi = 0; mi < MI; ++mi)
#pragma unroll
      for (int ni = 0; ni < 4; ++ni)
        acc[mi][ni] = mfma16(af[mi], bfr[ni], acc[mi][ni]);
    __syncthreads();
  }

#pragma unroll
  for (int mi = 0; mi < MI; ++mi)
#pragma unroll
    for (int ni = 0; ni < 4; ++ni) {
      const int col = n0 + wn + ni * 16 + lc;
      const float bv = bias[col];
      const int rbase = m0 + wm + mi * 16 + quad * 4;
      if (mode == 2) {
        float* out = (float*)Cout;
#pragma unroll
        for (int r = 0; r < 4; ++r)
          out[(size_t)(rbase + r) * D_ + col] = acc[mi][ni][r] + bv;
      } else if (mode == 0) {
        // Q/K swizzle: chunk = ((sl>>4)*2 + dk>>5)*64 + ((dk>>3)&3)*16 + (sl&15), elem +dk&7
        bf16* out = (bf16*)Cout;
        const int h = col >> 6, dk = col & 63;
        const int hh = dk >> 5, qk = (dk >> 3) & 3, j = dk & 7;
#pragma unroll
        for (int r = 0; r < 4; ++r) {
          const int m = rbase + r, bb = m >> 11, s = m & (S_ - 1);
          const int T = s >> 6, sl = s & 63;
          const size_t off = (size_t)(bb * H_ + h) * HEADELEMS + (size_t)T * TILEELEMS
                           + (size_t)((((sl >> 4) * 2 + hh) * 64 + qk * 16 + (sl & 15))) * 8 + j;
          out[off] = __float2bfloat16(acc[mi][ni][r] + bv);
        }
      } else {
        // V^T swizzle: c8 = ((sl>>4)*4 + dk>>4)*64 + ((sl>>2)&3)*16 + (dk&15), elem c8*4 + (sl&3)
        bf16* out = (bf16*)Cout;
        const int h = col >> 6, dk = col & 63;
        const int dkt = dk >> 4, lck = dk & 15;
        const int m = rbase, bb = m >> 11, s = m & (S_ - 1);
        const int T = s >> 6, sl = s & 63;
        const size_t off = (size_t)(bb * H_ + h) * HEADELEMS + (size_t)T * TILEELEMS
                         + (size_t)((((sl >> 4) * 4 + dkt) * 64 + ((sl >> 2) & 3) * 16 + lck)) * 4;
        bf16x4 pk = { __float2bfloat16(acc[mi][ni][0] + bv),
                      __float2bfloat16(acc[mi][ni][1] + bv),
                      __float2bfloat16(acc[mi][ni][2] + bv),
                      __float2bfloat16(acc[mi][ni][3] + bv) };
        *(bf16x4*)(out + off) = pk;
      }
    }
}

// ---------------- V suffix sums: suf[b][h][t][dk] = sum_{key >= t*64} V[key][dk] ----------------
__global__ void suf_kernel(const bf16* __restrict__ vp, float* __restrict__ suf) {
  __shared__ float ts[32 * 64];
  const int bhid = blockIdx.x;
  const bf16* vb = vp + (size_t)bhid * HEADELEMS;
  const int tid = threadIdx.x;
  const int dk = tid & 63, g = tid >> 6;
  const int dkt = dk >> 4, lck = dk & 15;
  for (int T = g * 8; T < g * 8 + 8; ++T) {
    float sum = 0.f;
#pragma unroll
    for (int w = 0; w < 4; ++w)
#pragma unroll
      for (int qd = 0; qd < 4; ++qd) {
        const s4v x = *(const s4v*)(vb + (size_t)T * TILEELEMS
                                    + (size_t)(((w * 4 + dkt) * 64 + qd * 16 + lck)) * 4);
        sum += bs2f(x[0]) + bs2f(x[1]) + bs2f(x[2]) + bs2f(x[3]);
      }
    ts[T * 64 + dk] = sum;
  }
  __syncthreads();
  if (g == 0) {
    float run = 0.f;
    float* out = suf + (size_t)bhid * (33 * 64);
    out[32 * 64 + dk] = 0.f;
    for (int T = 31; T >= 0; --T) { run += ts[T * 64 + dk]; out[T * 64 + dk] = run; }
  }
}

// ---------------- fused attention ----------------
__device__ __forceinline__ void load_pad(const void* pad, int bytemode, int idx, bool pm[4]) {
  if (bytemode) {
    const uchar4 u = *(const uchar4*)((const unsigned char*)pad + idx);
    pm[0] = u.x != 0; pm[1] = u.y != 0; pm[2] = u.z != 0; pm[3] = u.w != 0;
  } else {
    const int4 u = *(const int4*)((const int*)pad + idx);
    pm[0] = u.x != 0; pm[1] = u.y != 0; pm[2] = u.z != 0; pm[3] = u.w != 0;
  }
}

// S^T = K*Q^T for one 64-key tile (wave owns 16-key strip); mask+exp -> pf (P^T, B-frag-ready)
__device__ __forceinline__ void qk_tile(const bf16* ks, const short8 (&qf)[4][2],
                                        const bool pm[4], float (&lacc)[4], s4v (&pf)[4],
                                        const int w, const int lane, const int quad,
                                        const int lc, const bool diag) {
  const short8 ak0 = *(const short8*)(ks + (size_t)(w * 128 + lane) * 8);
  const short8 ak1 = *(const short8*)(ks + (size_t)(w * 128 + 64 + lane) * 8);
  const floatx4 z4 = {0.f, 0.f, 0.f, 0.f};
  const short ONE = (short)0x3F80;
#pragma unroll
  for (int qt = 0; qt < 4; ++qt) {
    if (diag && w > qt) {           // strictly-upper 16x16 subtile: all masked -> p = 1
      s4v o1 = {ONE, ONE, ONE, ONE};
      pf[qt] = o1;
      lacc[qt] += 4.f;
      continue;
    }
    floatx4 s = mfma16(ak0, qf[qt][0], z4);
    s = mfma16(ak1, qf[qt][1], s);
#pragma unroll
    for (int r = 0; r < 4; ++r) {
      bool m = pm[r];
      if (diag && w == qt) m = m || (quad * 4 + r > lc);
      const float sv = m ? 0.f : s[r] * 0.18033688f;   // 0.125*log2(e)
      const float pv = exp2f(sv);
      lacc[qt] += pv;
      pf[qt][r] = f2bs(pv);
    }
  }
}

__global__ __launch_bounds__(256, 3) void attn_kernel(
    const bf16* __restrict__ qp, const bf16* __restrict__ kp,
    const bf16* __restrict__ vp, const float* __restrict__ suf,
    const void* __restrict__ pad, const int* __restrict__ flag,
    bf16* __restrict__ oa)
{
  __shared__ __align__(16) bf16 smem[16384];   // [0,4096) K0 [4096,8192) K1 [8192,12288) V0 [12288,16384) V1
  __shared__ float lbuf[256];

  const int b = blockIdx.z, h = blockIdx.y;
  const int qt_blk = 31 - blockIdx.x;           // heaviest blocks dispatch first
  const int q0 = qt_blk * 64;
  const int nt = qt_blk + 1;                    // key tiles to process (triangular)
  const int tid = threadIdx.x;
  const int w = tid >> 6, lane = tid & 63, quad = lane >> 4, lc = lane & 15;
  const int bytemode = *flag;
  const int padbase = b * S_;
  const size_t bh = (size_t)(b * H_ + h);
  const bf16* kb = kp + bh * HEADELEMS;
  const bf16* vb = vp + bh * HEADELEMS;

  // Q fragments: all 64 q rows (B-operand for S^T = K*Q^T), swizzled-linear in global
  const bf16* qb = qp + bh * HEADELEMS + (size_t)qt_blk * TILEELEMS;
  short8 qf[4][2];
#pragma unroll
  for (int qt = 0; qt < 4; ++qt)
#pragma unroll
    for (int hh = 0; hh < 2; ++hh)
      qf[qt][hh] = *(const short8*)(qb + (size_t)((qt * 2 + hh) * 64 + lane) * 8);

  const floatx4 zero4 = {0.f, 0.f, 0.f, 0.f};
  floatx4 oacc[4][4];                            // [dkt][qt], O^T partial over this wave's keys
#pragma unroll
  for (int i = 0; i < 4; ++i)
#pragma unroll
    for (int j = 0; j < 4; ++j) oacc[i][j] = zero4;
  float lacc[4] = {0.f, 0.f, 0.f, 0.f};

  const int npairs = (nt + 1) >> 1;
  for (int p = 0; p < npairs; ++p) {
    const int T0v = 2 * p, T1v = 2 * p + 1;
    // stage K0,K1,V0,V1 (8KB each): fragment-linear, perfectly coalesced, conflict-free
#pragma unroll
    for (int i = 0; i < 2; ++i) {
      const int I = w * 2 + i;
      const size_t co = (size_t)(I * 64 + lane) * 8;
      gl_lds16(kb + (size_t)T0v * TILEELEMS + co, smem + I * 512);
      gl_lds16(kb + (size_t)T1v * TILEELEMS + co, smem + 4096 + I * 512);
      gl_lds16(vb + (size_t)T0v * TILEELEMS + co, smem + 8192 + I * 512);
      gl_lds16(vb + (size_t)T1v * TILEELEMS + co, smem + 12288 + I * 512);
    }
    __syncthreads();

    const bool last = (p == npairs - 1);
    bool pm[4];
    s4v pf0[4], pf1[4];
    load_pad(pad, bytemode, padbase + T0v * 64 + w * 16 + quad * 4, pm);
    qk_tile(smem, qf, pm, lacc, pf0, w, lane, quad, lc, last && (T0v == nt - 1));
    if (T1v < nt) {
      load_pad(pad, bytemode, padbase + T1v * 64 + w * 16 + quad * 4, pm);
      qk_tile(smem + 4096, qf, pm, lacc, pf1, w, lane, quad, lc, last && (T1v == nt - 1));
    } else {
      const s4v zz = {0, 0, 0, 0};
#pragma unroll
      for (int qt = 0; qt < 4; ++qt) pf1[qt] = zz;   // phantom tile: contributes 0 (covered by suffix)
    }

    // O^T += V^T * P^T  (k = the wave's 32 keys across the tile pair)
    short8 pB[4];
#pragma unroll
    for (int qt = 0; qt < 4; ++qt)
      pB[qt] = __builtin_shufflevector(pf0[qt], pf1[qt], 0, 1, 2, 3, 4, 5, 6, 7);
#pragma unroll
    for (int dkt = 0; dkt < 4; ++dkt) {
      const s4v a0 = *(const s4v*)(smem + 8192  + (size_t)((w * 4 + dkt) * 64 + lane) * 4);
      const s4v a1 = *(const s4v*)(smem + 12288 + (size_t)((w * 4 + dkt) * 64 + lane) * 4);
      const short8 av = __builtin_shufflevector(a0, a1, 0, 1, 2, 3, 4, 5, 6, 7);
#pragma unroll
      for (int qt = 0; qt < 4; ++qt)
        oacc[dkt][qt] = mfma16(av, pB[qt], oacc[dkt][qt]);
    }
    __syncthreads();
  }

  // ---- cross-wave reduction (4 key-strip partials), suffix add, normalize, store ----
  // l reduce: sum over quads in-register, waves via lbuf
#pragma unroll
  for (int qt = 0; qt < 4; ++qt) {
    float v = lacc[qt];
    v += __shfl_xor(v, 16);
    v += __shfl_xor(v, 32);
    if (quad == 0) lbuf[w * 64 + qt * 16 + lc] = v;
  }
  float* fbuf = (float*)smem;  // 8192 floats
  const float* sufp = suf + bh * (33 * 64) + nt * 64;
  const size_t orow = (size_t)(b * S_ + q0 + w * 16 + lc) * D_ + h * 64;

#pragma unroll
  for (int phase = 0; phase < 2; ++phase) {
    const int dkb = phase * 2;
    // write partials for dkt = dkb, dkb+1
#pragma unroll
    for (int dd = 0; dd < 2; ++dd)
#pragma unroll
      for (int qt = 0; qt < 4; ++qt) {
        const floatx4 a = oacc[dkb + dd][qt];
        float* dst = fbuf + ((w * 2 + dd) * 4 + qt) * 256 + lc;
#pragma unroll
        for (int r = 0; r < 4; ++r) dst[(quad * 4 + r) * 16] = a[r];
      }
    __syncthreads();
    // reduce: this wave handles qt == w (its 16 q columns), all dk
    float ls = lbuf[0 * 64 + w * 16 + lc] + lbuf[1 * 64 + w * 16 + lc]
             + lbuf[2 * 64 + w * 16 + lc] + lbuf[3 * 64 + w * 16 + lc];
    ls += (float)(S_ - nt * 64);               // keys beyond diagonal tile: weight 1 each
    const float linv = 1.f / ls;
#pragma unroll
    for (int dd = 0; dd < 2; ++dd) {
      const int dktG = dkb + dd;
      const float4 sv4 = *(const float4*)(sufp + dktG * 16 + quad * 4);
      float v[4];
#pragma unroll
      for (int r = 0; r < 4; ++r) {
        const int e = (quad * 4 + r) * 16 + lc;
        v[r] = fbuf[((0 * 2 + dd) * 4 + w) * 256 + e] + fbuf[((1 * 2 + dd) * 4 + w) * 256 + e]
             + fbuf[((2 * 2 + dd) * 4 + w) * 256 + e] + fbuf[((3 * 2 + dd) * 4 + w) * 256 + e];
      }
      v[0] = (v[0] + sv4.x) * linv; v[1] = (v[1] + sv4.y) * linv;
      v[2] = (v[2] + sv4.z) * linv; v[3] = (v[3] + sv4.w) * linv;
      bf16x4 pk = { __float2bfloat16(v[0]), __float2bfloat16(v[1]),
                    __float2bfloat16(v[2]), __float2bfloat16(v[3]) };
      *(bf16x4*)(oa + orow + dktG * 16 + quad * 4) = pk;
    }
    __syncthreads();
  }
}

extern "C" void kernel_launch(void* const* d_in, const int* in_sizes, int n_in,
                              void* d_out, int out_size, void* d_ws, size_t ws_size,
                              hipStream_t stream) {
  (void)in_sizes; (void)n_in; (void)out_size; (void)ws_size;
  const float* q_in = (const float*)d_in[0];
  const float* k_in = (const float*)d_in[1];
  const float* v_in = (const float*)d_in[2];
  const void*  pmask = d_in[3];
  const float* Wq = (const float*)d_in[4];
  const float* bq = (const float*)d_in[5];
  const float* Wk = (const float*)d_in[6];
  const float* bk = (const float*)d_in[7];
  const float* Wv = (const float*)d_in[8];
  const float* bv = (const float*)d_in[9];
  const float* Wo = (const float*)d_in[10];
  const float* bo = (const float*)d_in[11];

  char* ws = (char*)d_ws;
  bf16* xq  = (bf16*)(ws + 0);          // 8 MiB; reused as attention output oa
  bf16* xk  = (bf16*)(ws + 8388608);
  bf16* xv  = (bf16*)(ws + 16777216);
  bf16* wqt = (bf16*)(ws + 25165824);   // 2 MiB each; wqt region reused for suf after proj
  bf16* wkt = (bf16*)(ws + 27262976);
  bf16* wvt = (bf16*)(ws + 29360128);
  bf16* wot = (bf16*)(ws + 31457280);
  bf16* qpp = (bf16*)(ws + 33554432);   // 8 MiB, swizzled Q
  bf16* kpp = (bf16*)(ws + 41943040);   // 8 MiB, swizzled K
  bf16* vpp = (bf16*)(ws + 50331648);   // 8 MiB, swizzled V^T
  float* suf = (float*)(ws + 25165824); // 264 KiB (overlays wqt; written after proj reads it)
  int*  flg = (int*)(ws + 58720256);
  bf16* oa  = xq;

  const int n4 = (M_ * D_) / 4;
  convert3<<<dim3(4096, 1, 3), 256, 0, stream>>>(q_in, k_in, v_in, xq, xk, xv, n4);
  transpose4<<<dim3(16, 16, 4), 256, 0, stream>>>(Wq, Wk, Wv, Wo, wqt, wkt, wvt, wot);
  detect_mask<<<1, 256, 0, stream>>>((const unsigned int*)pmask, flg);

  gemm_k<128><<<dim3(8, 32, 3), 256, 0, stream>>>(xq, xk, xv, wqt, wkt, wvt,
                                                  bq, bk, bv, qpp, kpp, vpp, 0, D_);
  suf_kernel<<<32, 256, 0, stream>>>(vpp, suf);

  attn_kernel<<<dim3(32, 16, 2), 256, 0, stream>>>(qpp, kpp, vpp, suf, pmask, flg, oa);

  gemm_k<64><<<dim3(8, 64, 1), 256, 0, stream>>>(oa, oa, oa, wot, wot, wot,
                                                 bo, bo, bo, d_out, d_out, d_out, 2, D_);
}

// Round 3
// 273.525 us; speedup vs baseline: 1.3553x; 1.0093x over previous
//
#include <hip/hip_runtime.h>
#include <hip/hip_bf16.h>
#include <cstdint>
#include <cstddef>

typedef __hip_bfloat16 bf16;
typedef __attribute__((ext_vector_type(8))) short short8;   // 8 bf16 = 4 VGPRs
typedef __attribute__((ext_vector_type(4))) short s4v;      // 4 bf16 = 2 VGPRs
typedef __attribute__((ext_vector_type(4))) float floatx4;

#define B_ 2
#define S_ 2048
#define D_ 1024
#define H_ 16
#define DK_ 64
#define M_ 4096
#define HEADELEMS 131072   // S_*DK_ per (b,h)
#define TILEELEMS 4096     // 64*64 per 64-token tile

struct __align__(8) bf16x4 { bf16 x, y, z, w; };

__device__ __forceinline__ floatx4 mfma16(short8 a, short8 b, floatx4 c) {
  return __builtin_amdgcn_mfma_f32_16x16x32_bf16(a, b, c, 0, 0, 0);
}
__device__ __forceinline__ void gl_lds16(const bf16* g, bf16* l) {
  __builtin_amdgcn_global_load_lds((const __attribute__((address_space(1))) void*)g,
                                   (__attribute__((address_space(3))) void*)l, 16, 0, 0);
}
__device__ __forceinline__ short f2bs(float x) {
  bf16 b = __float2bfloat16(x);
  return *reinterpret_cast<short*>(&b);
}
__device__ __forceinline__ float bs2f(short s) {
  bf16 b = *reinterpret_cast<bf16*>(&s);
  return __bfloat162float(b);
}

// ---------------- fused fp32->bf16 converts (q,k,v inputs) ----------------
__global__ void convert3(const float* __restrict__ a0, const float* __restrict__ a1,
                         const float* __restrict__ a2, bf16* __restrict__ o0,
                         bf16* __restrict__ o1, bf16* __restrict__ o2, const int n4) {
  const int z = blockIdx.z;
  const float* src = (z == 0) ? a0 : (z == 1) ? a1 : a2;
  bf16* dst = (z == 0) ? o0 : (z == 1) ? o1 : o2;
  const int i = blockIdx.x * blockDim.x + threadIdx.x;
  if (i >= n4) return;
  float4 v = ((const float4*)src)[i];
  bf16x4 o = { __float2bfloat16(v.x), __float2bfloat16(v.y),
               __float2bfloat16(v.z), __float2bfloat16(v.w) };
  ((bf16x4*)dst)[i] = o;
}

// ---------------- fused weight transposes fp32 [R][C] -> bf16 [C][R] ----------------
__global__ void transpose4(const float* __restrict__ s0, const float* __restrict__ s1,
                           const float* __restrict__ s2, const float* __restrict__ s3,
                           bf16* __restrict__ d0, bf16* __restrict__ d1,
                           bf16* __restrict__ d2, bf16* __restrict__ d3) {
  const int z = blockIdx.z;
  const float* src = (z == 0) ? s0 : (z == 1) ? s1 : (z == 2) ? s2 : s3;
  bf16* dst = (z == 0) ? d0 : (z == 1) ? d1 : (z == 2) ? d2 : d3;
  __shared__ bf16 tile[64][66];
  const int r0 = blockIdx.y * 64, c0 = blockIdx.x * 64;
  const int tid = threadIdx.x;
  const int lr = tid >> 4;
  const int lc4 = (tid & 15) * 4;
#pragma unroll
  for (int i = 0; i < 4; ++i) {
    const int r = lr + i * 16;
    float4 v = *(const float4*)(src + (size_t)(r0 + r) * D_ + c0 + lc4);
    tile[r][lc4 + 0] = __float2bfloat16(v.x);
    tile[r][lc4 + 1] = __float2bfloat16(v.y);
    tile[r][lc4 + 2] = __float2bfloat16(v.z);
    tile[r][lc4 + 3] = __float2bfloat16(v.w);
  }
  __syncthreads();
  const int orr = tid & 63;
  const int oc0 = tid >> 6;
#pragma unroll
  for (int j = 0; j < 16; ++j) {
    const int oc = oc0 + j * 4;
    dst[(size_t)(c0 + oc) * D_ + r0 + orr] = tile[orr][oc];
  }
}

// ---------------- padding-mask dtype detector ----------------
__global__ void detect_mask(const unsigned int* __restrict__ p, int* __restrict__ flag) {
  __shared__ int sbyte;
  if (threadIdx.x == 0) sbyte = 0;
  __syncthreads();
  for (int i = threadIdx.x; i < (B_ * S_) / 4; i += 256) {
    const unsigned int v = p[i];
    if (((v & 0xFEFEFEFEu) == 0u) && ((v & 0xFFFFFF00u) != 0u)) sbyte = 1;
  }
  __syncthreads();
  if (threadIdx.x == 0) *flag = sbyte;
}

// ---------------- bf16 GEMM, C = A[M,K] * W[N,K]^T + bias ----------------
template<int MT>
__global__ __launch_bounds__(256, 2) void gemm_k(
    const bf16* __restrict__ A0, const bf16* __restrict__ A1, const bf16* __restrict__ A2,
    const bf16* __restrict__ W0, const bf16* __restrict__ W1, const bf16* __restrict__ W2,
    const float* __restrict__ b0, const float* __restrict__ b1, const float* __restrict__ b2,
    void* __restrict__ O0, void* __restrict__ O1, void* __restrict__ O2,
    const int mode01, const int Kd)
{
  __shared__ __align__(16) bf16 As[MT * 32];
  __shared__ __align__(16) bf16 Bs[128 * 32];
  const int z = blockIdx.z;
  const bf16* A = (z == 0) ? A0 : (z == 1) ? A1 : A2;
  const bf16* W = (z == 0) ? W0 : (z == 1) ? W1 : W2;
  const float* bias = (z == 0) ? b0 : (z == 1) ? b1 : b2;
  void* Cout = (z == 0) ? O0 : (z == 1) ? O1 : O2;
  const int mode = (z == 2) ? 1 : mode01;

  constexpr int MI = MT / 32;
  const int tid = threadIdx.x;
  const int wave = tid >> 6, lane = tid & 63;
  const int quad = lane >> 4, lc = lane & 15;
  const int wm = (wave >> 1) * (MT / 2), wn = (wave & 1) * 64;
  const int m0 = blockIdx.y * MT, n0 = blockIdx.x * 128;

  const floatx4 zero4 = {0.f, 0.f, 0.f, 0.f};
  floatx4 acc[MI][4];
#pragma unroll
  for (int mi = 0; mi < MI; ++mi)
#pragma unroll
    for (int ni = 0; ni < 4; ++ni) acc[mi][ni] = zero4;

  const int ldr = lane >> 2;
  const int ldc = (lane & 3) * 8;
  const bf16* Ag = A + (size_t)(m0 + wave * (MT / 4) + ldr) * Kd + ldc;
  const bf16* Bg = W + (size_t)(n0 + wave * 32 + ldr) * Kd + ldc;
  bf16* As0 = As + wave * (MT / 4) * 32;
  bf16* Bs0 = Bs + wave * 32 * 32;

  for (int k0 = 0; k0 < Kd; k0 += 32) {
    gl_lds16(Ag + k0, As0);
    if (MT == 128) gl_lds16(Ag + k0 + (size_t)16 * Kd, As0 + 16 * 32);
    gl_lds16(Bg + k0, Bs0);
    gl_lds16(Bg + k0 + (size_t)16 * Kd, Bs0 + 16 * 32);
    __syncthreads();

    short8 af[MI], bfr[4];
#pragma unroll
    for (int i = 0; i < MI; ++i)
      af[i] = *(const short8*)(As + (wm + i * 16 + lc) * 32 + quad * 8);
#pragma unroll
    for (int i = 0; i < 4; ++i)
      bfr[i] = *(const short8*)(Bs + (wn + i * 16 + lc) * 32 + quad * 8);
#pragma unroll
    for (int mi = 0; mi < MI; ++mi)
#pragma unroll
      for (int ni = 0; ni < 4; ++ni)
        acc[mi][ni] = mfma16(af[mi], bfr[ni], acc[mi][ni]);
    __syncthreads();
  }

#pragma unroll
  for (int mi = 0; mi < MI; ++mi)
#pragma unroll
    for (int ni = 0; ni < 4; ++ni) {
      const int col = n0 + wn + ni * 16 + lc;
      const float bv = bias[col];
      const int rbase = m0 + wm + mi * 16 + quad * 4;
      if (mode == 2) {
        float* out = (float*)Cout;
#pragma unroll
        for (int r = 0; r < 4; ++r)
          out[(size_t)(rbase + r) * D_ + col] = acc[mi][ni][r] + bv;
      } else if (mode == 0) {
        bf16* out = (bf16*)Cout;
        const int h = col >> 6, dk = col & 63;
        const int hh = dk >> 5, qk = (dk >> 3) & 3, j = dk & 7;
#pragma unroll
        for (int r = 0; r < 4; ++r) {
          const int m = rbase + r, bb = m >> 11, s = m & (S_ - 1);
          const int T = s >> 6, sl = s & 63;
          const size_t off = (size_t)(bb * H_ + h) * HEADELEMS + (size_t)T * TILEELEMS
                           + (size_t)((((sl >> 4) * 2 + hh) * 64 + qk * 16 + (sl & 15))) * 8 + j;
          out[off] = __float2bfloat16(acc[mi][ni][r] + bv);
        }
      } else {
        bf16* out = (bf16*)Cout;
        const int h = col >> 6, dk = col & 63;
        const int dkt = dk >> 4, lck = dk & 15;
        const int m = rbase, bb = m >> 11, s = m & (S_ - 1);
        const int T = s >> 6, sl = s & 63;
        const size_t off = (size_t)(bb * H_ + h) * HEADELEMS + (size_t)T * TILEELEMS
                         + (size_t)((((sl >> 4) * 4 + dkt) * 64 + ((sl >> 2) & 3) * 16 + lck)) * 4;
        bf16x4 pk = { __float2bfloat16(acc[mi][ni][0] + bv),
                      __float2bfloat16(acc[mi][ni][1] + bv),
                      __float2bfloat16(acc[mi][ni][2] + bv),
                      __float2bfloat16(acc[mi][ni][3] + bv) };
        *(bf16x4*)(out + off) = pk;
      }
    }
}

// ---------------- V suffix sums ----------------
__global__ void suf_kernel(const bf16* __restrict__ vp, float* __restrict__ suf) {
  __shared__ float ts[32 * 64];
  const int bhid = blockIdx.x;
  const bf16* vb = vp + (size_t)bhid * HEADELEMS;
  const int tid = threadIdx.x;
  const int dk = tid & 63, g = tid >> 6;
  const int dkt = dk >> 4, lck = dk & 15;
  for (int T = g * 8; T < g * 8 + 8; ++T) {
    float sum = 0.f;
#pragma unroll
    for (int w = 0; w < 4; ++w)
#pragma unroll
      for (int qd = 0; qd < 4; ++qd) {
        const s4v x = *(const s4v*)(vb + (size_t)T * TILEELEMS
                                    + (size_t)(((w * 4 + dkt) * 64 + qd * 16 + lck)) * 4);
        sum += bs2f(x[0]) + bs2f(x[1]) + bs2f(x[2]) + bs2f(x[3]);
      }
    ts[T * 64 + dk] = sum;
  }
  __syncthreads();
  if (g == 0) {
    float run = 0.f;
    float* out = suf + (size_t)bhid * (33 * 64);
    out[32 * 64 + dk] = 0.f;
    for (int T = 31; T >= 0; --T) { run += ts[T * 64 + dk]; out[T * 64 + dk] = run; }
  }
}

// ---------------- fused attention (balanced pair-of-q-tiles, wave-specialized) ----------------
__device__ __forceinline__ void load_pad(const void* pad, int bytemode, int idx, bool pm[4]) {
  if (bytemode) {
    const uchar4 u = *(const uchar4*)((const unsigned char*)pad + idx);
    pm[0] = u.x != 0; pm[1] = u.y != 0; pm[2] = u.z != 0; pm[3] = u.w != 0;
  } else {
    const int4 u = *(const int4*)((const int*)pad + idx);
    pm[0] = u.x != 0; pm[1] = u.y != 0; pm[2] = u.z != 0; pm[3] = u.w != 0;
  }
}

__device__ __forceinline__ void qk_tile(const short8 ak0, const short8 ak1,
                                        const short8 (&qf)[4][2],
                                        const bool pm[4], float (&lacc)[4], s4v (&pf)[4],
                                        const int ws, const int quad, const int lc,
                                        const bool diag) {
  const floatx4 z4 = {0.f, 0.f, 0.f, 0.f};
  const short ONE = (short)0x3F80;
#pragma unroll
  for (int qt = 0; qt < 4; ++qt) {
    if (diag && ws > qt) {          // strictly-upper 16x16 subtile: all masked -> p = 1
      s4v o1 = {ONE, ONE, ONE, ONE};
      pf[qt] = o1;
      lacc[qt] += 4.f;
      continue;
    }
    floatx4 s = mfma16(ak0, qf[qt][0], z4);
    s = mfma16(ak1, qf[qt][1], s);
#pragma unroll
    for (int r = 0; r < 4; ++r) {
      bool m = pm[r];
      if (diag && ws == qt) m = m || (quad * 4 + r > lc);
      const float sv = m ? 0.f : s[r] * 0.18033688f;   // 0.125*log2(e)
      const float pv = exp2f(sv);
      lacc[qt] += pv;
      pf[qt][r] = f2bs(pv);
    }
  }
}

// block handles q-tiles {31-j (waves 0-3), j (waves 4-7)}: constant 33 tiles of work.
// K/V staged once per key-tile pair, shared by both q-sets; double-buffered.
__global__ __launch_bounds__(512, 4) void attn_kernel(
    const bf16* __restrict__ qp, const bf16* __restrict__ kp,
    const bf16* __restrict__ vp, const float* __restrict__ suf,
    const void* __restrict__ pad, const int* __restrict__ flag,
    bf16* __restrict__ oa)
{
  __shared__ __align__(16) bf16 smem[2][16384];  // per buf: K0,K1,V0,V1 (8KB each)
  __shared__ float lbuf[512];

  const int b = blockIdx.z, h = blockIdx.y, j = blockIdx.x;
  const int tid = threadIdx.x;
  const int w = tid >> 6, lane = tid & 63, quad = lane >> 4, lc = lane & 15;
  const int qset = w >> 2, ws = w & 3;
  const int myqt = (qset == 0) ? (31 - j) : j;
  const int mynt = (qset == 0) ? (32 - j) : (j + 1);
  const int mynp = (mynt + 1) >> 1;
  const int npB  = (32 - j + 1) >> 1;           // loop trip count (big set)
  const int bytemode = *flag;
  const int padbase = b * S_;
  const size_t bh = (size_t)(b * H_ + h);
  const bf16* kb = kp + bh * HEADELEMS;
  const bf16* vb = vp + bh * HEADELEMS;

  // Q fragments for this wave's q-tile (B-operand for S^T = K*Q^T)
  const bf16* qb = qp + bh * HEADELEMS + (size_t)myqt * TILEELEMS;
  short8 qf[4][2];
#pragma unroll
  for (int qt = 0; qt < 4; ++qt)
#pragma unroll
    for (int hh = 0; hh < 2; ++hh)
      qf[qt][hh] = *(const short8*)(qb + (size_t)((qt * 2 + hh) * 64 + lane) * 8);

  const floatx4 zero4 = {0.f, 0.f, 0.f, 0.f};
  floatx4 oacc[4][4];                            // [dkt][qt]
#pragma unroll
  for (int i = 0; i < 4; ++i)
#pragma unroll
    for (int jj = 0; jj < 4; ++jj) oacc[i][jj] = zero4;
  float lacc[4] = {0.f, 0.f, 0.f, 0.f};

  const size_t co = (size_t)(w * 64 + lane) * 8;   // this wave's 1KB staging chunk

  // prologue: stage pair 0 into buf 0
  {
    bf16* dst = smem[0];
    gl_lds16(kb + co,                          dst + w * 512);
    gl_lds16(kb + TILEELEMS + co,              dst + 4096 + w * 512);
    gl_lds16(vb + co,                          dst + 8192 + w * 512);
    gl_lds16(vb + TILEELEMS + co,              dst + 12288 + w * 512);
  }

  for (int p = 0; p < npB; ++p) {
    __syncthreads();                            // drains stage of pair p
    if (p + 1 < npB) {                          // prefetch pair p+1 (overlaps compute)
      bf16* dst = smem[(p + 1) & 1];
      const size_t t0 = (size_t)(2 * p + 2) * TILEELEMS;
      const size_t t1 = (size_t)(2 * p + 3) * TILEELEMS;
      gl_lds16(kb + t0 + co, dst + w * 512);
      gl_lds16(kb + t1 + co, dst + 4096 + w * 512);
      gl_lds16(vb + t0 + co, dst + 8192 + w * 512);
      gl_lds16(vb + t1 + co, dst + 12288 + w * 512);
    }
    if (p < mynp) {
      const bf16* cur = smem[p & 1];
      const int T0 = 2 * p, T1 = 2 * p + 1;
      // K fragments for this wave's key strip, both tiles
      const short8 ak00 = *(const short8*)(cur + (size_t)(ws * 128 + lane) * 8);
      const short8 ak01 = *(const short8*)(cur + (size_t)(ws * 128 + 64 + lane) * 8);
      const short8 ak10 = *(const short8*)(cur + 4096 + (size_t)(ws * 128 + lane) * 8);
      const short8 ak11 = *(const short8*)(cur + 4096 + (size_t)(ws * 128 + 64 + lane) * 8);

      bool pm[4];
      s4v pf0[4], pf1[4];
      load_pad(pad, bytemode, padbase + T0 * 64 + ws * 16 + quad * 4, pm);
      qk_tile(ak00, ak01, qf, pm, lacc, pf0, ws, quad, lc, T0 == mynt - 1);
      if (T1 < mynt) {
        load_pad(pad, bytemode, padbase + T1 * 64 + ws * 16 + quad * 4, pm);
        qk_tile(ak10, ak11, qf, pm, lacc, pf1, ws, quad, lc, T1 == mynt - 1);
      } else {
        const s4v zz = {0, 0, 0, 0};
#pragma unroll
        for (int qt = 0; qt < 4; ++qt) pf1[qt] = zz;   // phantom: covered by suffix
      }

      short8 pB[4];
#pragma unroll
      for (int qt = 0; qt < 4; ++qt)
        pB[qt] = __builtin_shufflevector(pf0[qt], pf1[qt], 0, 1, 2, 3, 4, 5, 6, 7);
#pragma unroll
      for (int dkt = 0; dkt < 4; ++dkt) {
        const s4v a0 = *(const s4v*)(cur + 8192  + (size_t)((ws * 4 + dkt) * 64 + lane) * 4);
        const s4v a1 = *(const s4v*)(cur + 12288 + (size_t)((ws * 4 + dkt) * 64 + lane) * 4);
        const short8 av = __builtin_shufflevector(a0, a1, 0, 1, 2, 3, 4, 5, 6, 7);
#pragma unroll
        for (int qt = 0; qt < 4; ++qt)
          oacc[dkt][qt] = mfma16(av, pB[qt], oacc[dkt][qt]);
      }
    }
  }

  // ---- epilogue: per-qset cross-wave reduction, suffix add, normalize, store ----
#pragma unroll
  for (int qt = 0; qt < 4; ++qt) {
    float v = lacc[qt];
    v += __shfl_xor(v, 16);
    v += __shfl_xor(v, 32);
    if (quad == 0) lbuf[qset * 256 + ws * 64 + qt * 16 + lc] = v;
  }
  __syncthreads();                               // all staging/compute done; reuse smem
  float* fbuf = (float*)(&smem[0][0]) + qset * 8192;   // 32KB per qset
  const float* sufp = suf + bh * (33 * 64) + mynt * 64;
  const size_t orow = (size_t)(b * S_ + myqt * 64 + ws * 16 + lc) * D_ + h * 64;

#pragma unroll
  for (int phase = 0; phase < 2; ++phase) {
    const int dkb = phase * 2;
#pragma unroll
    for (int dd = 0; dd < 2; ++dd)
#pragma unroll
      for (int qt = 0; qt < 4; ++qt) {
        const floatx4 a = oacc[dkb + dd][qt];
        float* dst = fbuf + ((ws * 2 + dd) * 4 + qt) * 256 + lc;
#pragma unroll
        for (int r = 0; r < 4; ++r) dst[(quad * 4 + r) * 16] = a[r];
      }
    __syncthreads();
    float ls = lbuf[qset * 256 + 0 * 64 + ws * 16 + lc] + lbuf[qset * 256 + 1 * 64 + ws * 16 + lc]
             + lbuf[qset * 256 + 2 * 64 + ws * 16 + lc] + lbuf[qset * 256 + 3 * 64 + ws * 16 + lc];
    ls += (float)(S_ - mynt * 64);
    const float linv = 1.f / ls;
#pragma unroll
    for (int dd = 0; dd < 2; ++dd) {
      const int dktG = dkb + dd;
      const float4 sv4 = *(const float4*)(sufp + dktG * 16 + quad * 4);
      float v[4];
#pragma unroll
      for (int r = 0; r < 4; ++r) {
        const int e = (quad * 4 + r) * 16 + lc;
        v[r] = fbuf[((0 * 2 + dd) * 4 + ws) * 256 + e] + fbuf[((1 * 2 + dd) * 4 + ws) * 256 + e]
             + fbuf[((2 * 2 + dd) * 4 + ws) * 256 + e] + fbuf[((3 * 2 + dd) * 4 + ws) * 256 + e];
      }
      v[0] = (v[0] + sv4.x) * linv; v[1] = (v[1] + sv4.y) * linv;
      v[2] = (v[2] + sv4.z) * linv; v[3] = (v[3] + sv4.w) * linv;
      bf16x4 pk = { __float2bfloat16(v[0]), __float2bfloat16(v[1]),
                    __float2bfloat16(v[2]), __float2bfloat16(v[3]) };
      *(bf16x4*)(oa + orow + dktG * 16 + quad * 4) = pk;
    }
    __syncthreads();
  }
}

extern "C" void kernel_launch(void* const* d_in, const int* in_sizes, int n_in,
                              void* d_out, int out_size, void* d_ws, size_t ws_size,
                              hipStream_t stream) {
  (void)in_sizes; (void)n_in; (void)out_size; (void)ws_size;
  const float* q_in = (const float*)d_in[0];
  const float* k_in = (const float*)d_in[1];
  const float* v_in = (const float*)d_in[2];
  const void*  pmask = d_in[3];
  const float* Wq = (const float*)d_in[4];
  const float* bq = (const float*)d_in[5];
  const float* Wk = (const float*)d_in[6];
  const float* bk = (const float*)d_in[7];
  const float* Wv = (const float*)d_in[8];
  const float* bv = (const float*)d_in[9];
  const float* Wo = (const float*)d_in[10];
  const float* bo = (const float*)d_in[11];

  char* ws = (char*)d_ws;
  bf16* xq  = (bf16*)(ws + 0);
  bf16* xk  = (bf16*)(ws + 8388608);
  bf16* xv  = (bf16*)(ws + 16777216);
  bf16* wqt = (bf16*)(ws + 25165824);
  bf16* wkt = (bf16*)(ws + 27262976);
  bf16* wvt = (bf16*)(ws + 29360128);
  bf16* wot = (bf16*)(ws + 31457280);
  bf16* qpp = (bf16*)(ws + 33554432);
  bf16* kpp = (bf16*)(ws + 41943040);
  bf16* vpp = (bf16*)(ws + 50331648);
  float* suf = (float*)(ws + 25165824);   // overlays wqt (dead after projections)
  int*  flg = (int*)(ws + 58720256);
  bf16* oa  = xq;

  const int n4 = (M_ * D_) / 4;
  convert3<<<dim3(4096, 1, 3), 256, 0, stream>>>(q_in, k_in, v_in, xq, xk, xv, n4);
  transpose4<<<dim3(16, 16, 4), 256, 0, stream>>>(Wq, Wk, Wv, Wo, wqt, wkt, wvt, wot);
  detect_mask<<<1, 256, 0, stream>>>((const unsigned int*)pmask, flg);

  gemm_k<128><<<dim3(8, 32, 3), 256, 0, stream>>>(xq, xk, xv, wqt, wkt, wvt,
                                                  bq, bk, bv, qpp, kpp, vpp, 0, D_);
  suf_kernel<<<32, 256, 0, stream>>>(vpp, suf);

  attn_kernel<<<dim3(16, 16, 2), 512, 0, stream>>>(qpp, kpp, vpp, suf, pmask, flg, oa);

  gemm_k<64><<<dim3(8, 64, 1), 256, 0, stream>>>(oa, oa, oa, wot, wot, wot,
                                                 bo, bo, bo, d_out, d_out, d_out, 2, D_);
}